// Round 12
// baseline (217.712 us; speedup 1.0000x reference)
//
#include <hip/hip_runtime.h>
#include <stdint.h>

// AAM-Softmax fused: loss + acc for B=1024, C=100000, D=256.
//   k_prep (single launch, 3 grid segments):
//     [0,64):        L2-normalize emb rows -> fp8 e4m3 fragment layout
//     [64,6464):     L2-normalize wgt rows -> fp8 (rows >= 100000 zero-fill)
//     [6464,6528):   per-row target cos in fp32 (exact loss term) + p_u
//   Inputs scaled by sqrt(30*log2e) so fp8 MFMA emits acc = 30*log2e*cos
//   -> hot epilogue is exp2+add+max, UNSHIFTED domain (max p = e^30, fp32-ok).
//   k_main: R11 structure with ONE change: class-tile loop unrolled x2 with
//     TWO INDEPENDENT accumulator chains. Cross-round audit (R6<59, R8 64.7,
//     R11 60.1) shows ~60us regardless of B volume or epilogue size while
//     MfmaUtil sits at 35% vs the 26us MFMA floor -> latency-bound on the
//     8-deep dependent MFMA chain per tile. Two interleaved chains double
//     per-wave ILP; VGPR headroom exists (R11: 28 regs). launch_bounds(256,4)
//     = 128-VGPR cap so the ~80-reg footprint cannot spill (R7 lesson).
//   k_final: reduce 256 partials/row; pads contribute exp2(0)=1.0 exactly
//     -> subtract constant 2400; S' = S - 2400 - p_u + p_adj;
//     loss = log(S') - 30*tl; acc via max compare; mean.
#define DIM    256
#define BATCH  1024
#define NCLS   100000
#define NCT    256                     // class groups
#define TPG    25                      // 16-class tiles per group
#define NCLS_PAD (NCT * TPG * 16)      // 102400
#define PADC   2400.0f                 // pad classes' exact sum contribution
#define RG     16                      // row groups (64 rows per block)
#define WGTBLK (NCLS_PAD / 16)         // 6400 weight tiles
#define CLIPV  0.9999999f              // 1 - 1e-7 (matches ref fp32 clip)
#define COSM   0.98006657784124163f    // cos(0.2)
#define SINM   0.19866933079506122f    // sin(0.2)
#define K30L2E 43.280851226668903f     // 30 * log2(e)
#define SQK    6.5788184f              // sqrt(30*log2(e)) input pre-scale

typedef __attribute__((ext_vector_type(4))) float floatx4;
typedef __attribute__((ext_vector_type(2))) unsigned long ulong2v;  // 16 B

// ws layout (~28.6 MB)
#define EMBF_OFF 0                                    // 256 KB fp8 emb frags
#define WGTF_OFF (256 * 1024)                         // 26.2 MB fp8 wgt frags
#define TL_OFF   (WGTF_OFF + (size_t)NCLS_PAD * DIM)  // 4 KB adj target cos
#define PU_OFF   (TL_OFF + 4096)                      // 4 KB unadj target p
#define SP_OFF   (PU_OFF + 4096)                      // 256x1024 f32 partials
#define MP_OFF   (SP_OFF + (size_t)NCT * BATCH * 4)   // 256x1024 u32 partials

// ---- k_prep: one launch, three segments ----------------------------------
// Fragment layout: byte (row,k) -> tile(row>>4)*4096 + (s>>1)*1024 + lane*16
// + (s&1)*8 + (k&7), s=k>>5, lane=(row&15)+16*((k>>3)&3).
__global__ __launch_bounds__(256) void k_prep(
        const float* __restrict__ emb, const float* __restrict__ wgt,
        const int* __restrict__ labels,
        unsigned char* __restrict__ emb8f, unsigned char* __restrict__ wgt8f,
        float* __restrict__ TL, float* __restrict__ PU) {
    const int b = blockIdx.x;
    const int tid = threadIdx.x;
    const int w = tid >> 6, l = tid & 63;
    const int sub = w * 4 + (l >> 4);             // row-in-block 0..15
    const int l16 = l & 15;                       // 16 floats per lane

    if (b < 64 + WGTBLK) {                        // --- normalize -> fp8 ---
        const bool isEmb = (b < 64);
        const float* src = isEmb ? emb : wgt;
        unsigned char* dst = isEmb ? emb8f : wgt8f;
        const int nvalid = isEmb ? BATCH : NCLS;
        const int r = (isEmb ? b : b - 64) * 16 + sub;
        const int r16 = r & 15;
        float v[16];
        float ss = 0.f;
        if (r < nvalid) {
            const float* rp = src + (size_t)r * DIM + l16 * 16;
#pragma unroll
            for (int i = 0; i < 4; ++i) {
                float4 a = *(const float4*)(rp + i * 4);
                v[i*4+0]=a.x; v[i*4+1]=a.y; v[i*4+2]=a.z; v[i*4+3]=a.w;
                ss += a.x*a.x + a.y*a.y + a.z*a.z + a.w*a.w;
            }
        } else {
#pragma unroll
            for (int i = 0; i < 16; ++i) v[i] = 0.f;   // pad class -> zeros
        }
#pragma unroll
        for (int k = 1; k < 16; k <<= 1) ss += __shfl_xor(ss, k);
        // scale by SQK so A.B = 30*log2e*cos  (exp2(acc) needs no shift)
        const float sc = SQK / fmaxf(sqrtf(ss), 1e-12f);
        unsigned char* tb = dst + (size_t)(r >> 4) * 4096;
#pragma unroll
        for (int h = 0; h < 2; ++h) {             // two 8-byte k-groups/lane
            const int g = 2 * l16 + h;            // k = 8g..8g+7
            const int s = g >> 2, q = g & 3;
            int p0 = 0, p1 = 0;
            p0 = __builtin_amdgcn_cvt_pk_fp8_f32(v[h*8+0]*sc, v[h*8+1]*sc, p0, false);
            p0 = __builtin_amdgcn_cvt_pk_fp8_f32(v[h*8+2]*sc, v[h*8+3]*sc, p0, true);
            p1 = __builtin_amdgcn_cvt_pk_fp8_f32(v[h*8+4]*sc, v[h*8+5]*sc, p1, false);
            p1 = __builtin_amdgcn_cvt_pk_fp8_f32(v[h*8+6]*sc, v[h*8+7]*sc, p1, true);
            uint2 o; o.x = (unsigned)p0; o.y = (unsigned)p1;
            *(uint2*)(tb + (s >> 1) * 1024 + (r16 + 16 * q) * 16 + (s & 1) * 8) = o;
        }
    } else {                                      // --- target row pass ---
        const int r = (b - 64 - WGTBLK) * 16 + sub;
        const int lbl = labels[r];
        const float* ep = emb + (size_t)r * DIM + l16 * 16;
        const float* wp = wgt + (size_t)lbl * DIM + l16 * 16;
        float de = 0.f, dw = 0.f, dd = 0.f;
#pragma unroll
        for (int i = 0; i < 4; ++i) {
            float4 a = *(const float4*)(ep + i * 4);
            float4 bq = *(const float4*)(wp + i * 4);
            de += a.x*a.x + a.y*a.y + a.z*a.z + a.w*a.w;
            dw += bq.x*bq.x + bq.y*bq.y + bq.z*bq.z + bq.w*bq.w;
            dd += a.x*bq.x + a.y*bq.y + a.z*bq.z + a.w*bq.w;
        }
#pragma unroll
        for (int k = 1; k < 16; k <<= 1) {
            de += __shfl_xor(de, k); dw += __shfl_xor(dw, k); dd += __shfl_xor(dd, k);
        }
        if (l16 == 0) {
            float t = dd / (fmaxf(sqrtf(de), 1e-12f) * fmaxf(sqrtf(dw), 1e-12f));
            t = fminf(fmaxf(t, -CLIPV), CLIPV);
            PU[r] = __builtin_amdgcn_exp2f(t * K30L2E);   // unadjusted p
            TL[r] = t * COSM - sqrtf(fmaxf(1.f - t * t, 0.f)) * SINM;
        }
    }
}

// ---------------- k_main: fused GEMM + register softmax partials ----------
// R11 + class-tile loop unrolled x2 with independent accumulator chains.
__global__ __launch_bounds__(256, 4) void k_main(
        const unsigned char* __restrict__ wgt8f,
        const unsigned char* __restrict__ emb8f,
        float* __restrict__ SP, unsigned* __restrict__ MP) {
    const int cg = blockIdx.x;            // class group; XCD = blockid % 8
    const int rg = blockIdx.y;            // row group 0..15
    const int tid = threadIdx.x;
    const int w = tid >> 6, l = tid & 63;
    const int r16 = l & 15, q = l >> 4;
    const int rowbase = rg * 64 + w * 16;    // wave's 16 rows (1 M-tile)

    // A-fragments held in registers the whole kernel (fragment layout)
    long af[8];
    {
        const ulong2v* ap =
            (const ulong2v*)(emb8f + (size_t)(rowbase >> 4) * 4096) + l;
#pragma unroll
        for (int p = 0; p < 4; ++p) {
            ulong2v v = ap[p * 64];
            af[2*p]   = (long)v.x;
            af[2*p+1] = (long)v.y;
        }
    }

    float sum[4] = {0.f, 0.f, 0.f, 0.f};
    float mx [4] = {0.f, 0.f, 0.f, 0.f};   // max of p (monotone in logit)

    const ulong2v* bp = (const ulong2v*)(wgt8f + (size_t)(cg * TPG) * 4096) + l;
    // 12 paired iterations (two independent MFMA chains) + 1 tail tile
#pragma unroll 1
    for (int t = 0; t < TPG - 1; t += 2, bp += 512) {
        long bf0[8], bf1[8];
#pragma unroll
        for (int p = 0; p < 4; ++p) {             // 8 x 1KB coalesced
            ulong2v v0 = bp[p * 64];
            ulong2v v1 = bp[256 + p * 64];
            bf0[2*p]   = (long)v0.x;
            bf0[2*p+1] = (long)v0.y;
            bf1[2*p]   = (long)v1.x;
            bf1[2*p+1] = (long)v1.y;
        }
        floatx4 acc0 = {0.f, 0.f, 0.f, 0.f};
        floatx4 acc1 = {0.f, 0.f, 0.f, 0.f};
#pragma unroll
        for (int s = 0; s < 8; ++s) {             // two chains interleave
            acc0 = __builtin_amdgcn_mfma_f32_16x16x32_fp8_fp8(af[s], bf0[s], acc0, 0, 0, 0);
            acc1 = __builtin_amdgcn_mfma_f32_16x16x32_fp8_fp8(af[s], bf1[s], acc1, 0, 0, 0);
        }
        // acc = 30*log2e*cos; raw v_exp_f32; 8 independent exps batch.
#pragma unroll
        for (int r = 0; r < 4; ++r) {
            const float p0 = __builtin_amdgcn_exp2f(acc0[r]);
            const float p1 = __builtin_amdgcn_exp2f(acc1[r]);
            sum[r] += p0 + p1;
            mx[r] = fmaxf(mx[r], fmaxf(p0, p1));
        }
    }
    {   // tail tile (TPG = 25 is odd)
        long bf[8];
#pragma unroll
        for (int p = 0; p < 4; ++p) {
            ulong2v v = bp[p * 64];
            bf[2*p]   = (long)v.x;
            bf[2*p+1] = (long)v.y;
        }
        floatx4 acc = {0.f, 0.f, 0.f, 0.f};
#pragma unroll
        for (int s = 0; s < 8; ++s)
            acc = __builtin_amdgcn_mfma_f32_16x16x32_fp8_fp8(af[s], bf[s], acc, 0, 0, 0);
#pragma unroll
        for (int r = 0; r < 4; ++r) {
            const float p = __builtin_amdgcn_exp2f(acc[r]);
            sum[r] += p;
            mx[r] = fmaxf(mx[r], p);
        }
    }

    // one butterfly per wave (over the 16 class-columns)
#pragma unroll
    for (int k = 1; k < 16; k <<= 1)
#pragma unroll
        for (int r = 0; r < 4; ++r) {
            sum[r] += __shfl_xor(sum[r], k);
            mx[r] = fmaxf(mx[r], __shfl_xor(mx[r], k));
        }
    if (r16 < 4) {
        float sv = sum[0], mv = mx[0];
        if (r16 == 1) { sv = sum[1]; mv = mx[1]; }
        else if (r16 == 2) { sv = sum[2]; mv = mx[2]; }
        else if (r16 == 3) { sv = sum[3]; mv = mx[3]; }
        const int row = rowbase + q * 4 + r16;
        SP[cg * BATCH + row] = sv;
        MP[cg * BATCH + row] = __float_as_uint(mv);
    }
}

// ---------------- k_final: reduce partials + loss/acc + mean -------------
__global__ __launch_bounds__(256) void k_final(
        const float* __restrict__ SP, const unsigned* __restrict__ MP,
        const float* __restrict__ TL, const float* __restrict__ PU,
        float* __restrict__ out) {
    __shared__ float    ls[16][16];
    __shared__ unsigned lm[16][16];
    const int tid = threadIdx.x;
    const int r16 = tid & 15;                 // row within block
    const int c   = tid >> 4;                 // partial-chunk lane
    const int row = blockIdx.x * 16 + r16;
    float s = 0.f;
    unsigned m = 0u;
    for (int b = c; b < NCT; b += 16) {       // 16 iters, 64B-coalesced
        s += SP[(size_t)b * BATCH + row];
        const unsigned v = MP[(size_t)b * BATCH + row];
        m = v > m ? v : m;
    }
    ls[c][r16] = s; lm[c][r16] = m;
    __syncthreads();
    float loss = 0.f, corr = 0.f;
    if (tid < 16) {
        float st = 0.f; unsigned mt = 0u;
#pragma unroll
        for (int i = 0; i < 16; ++i) {
            st += ls[i][tid];
            mt = lm[i][tid] > mt ? lm[i][tid] : mt;
        }
        const int r = blockIdx.x * 16 + tid;
        const float tl = TL[r];
        const float padj = __builtin_amdgcn_exp2f(tl * K30L2E);
        // pads contribute exp2(0)=1.0 exactly -> subtract the constant;
        // swap target p: unadjusted -> margin-adjusted
        st = st - PADC - PU[r] + padj;
        loss = logf(st) - 30.f * tl;          // logsumexp - target logit
        corr = (padj >= __uint_as_float(mt)) ? 1.f : 0.f;  // pads (p=1) never win max
    }
#pragma unroll
    for (int k = 1; k < 16; k <<= 1) {        // lanes 16..63 carry zeros
        loss += __shfl_xor(loss, k);
        corr += __shfl_xor(corr, k);
    }
    if (tid == 0) {
        atomicAdd(out + 0, loss * (1.f / 1024.f));
        atomicAdd(out + 1, corr * (1.f / 1024.f));
    }
}

extern "C" void kernel_launch(void* const* d_in, const int* in_sizes, int n_in,
                              void* d_out, int out_size, void* d_ws, size_t ws_size,
                              hipStream_t stream) {
    (void)in_sizes; (void)n_in; (void)out_size; (void)ws_size;
    const float* emb    = (const float*)d_in[0];
    const float* wgt    = (const float*)d_in[1];
    const int*   labels = (const int*)d_in[2];
    char* ws = (char*)d_ws;
    unsigned char* emb8f = (unsigned char*)(ws + EMBF_OFF);
    unsigned char* wgt8f = (unsigned char*)(ws + WGTF_OFF);
    float*    TL = (float*)(ws + TL_OFF);
    float*    PU = (float*)(ws + PU_OFF);
    float*    SP = (float*)(ws + SP_OFF);
    unsigned* MP = (unsigned*)(ws + MP_OFF);

    hipMemsetAsync(d_out, 0, 2 * sizeof(float), stream);  // k_final accumulates
    k_prep<<<64 + WGTBLK + 64, 256, 0, stream>>>(emb, wgt, labels,
                                                 emb8f, wgt8f, TL, PU);
    k_main<<<dim3(NCT, RG), 256, 0, stream>>>(wgt8f, emb8f, SP, MP);
    k_final<<<64, 256, 0, stream>>>(SP, MP, TL, PU, (float*)d_out);
}

// Round 13
// 209.053 us; speedup vs baseline: 1.0414x; 1.0414x over previous
//
#include <hip/hip_runtime.h>
#include <stdint.h>

// AAM-Softmax fused: loss + acc for B=1024, C=100000, D=256.
//   k_prep (single launch, 3 grid segments):
//     [0,64):        L2-normalize emb rows -> fp8 e4m3 fragment layout
//     [64,6464):     L2-normalize wgt rows -> fp8 (rows >= 100000 zero-fill)
//     [6464,6528):   per-row target cos in fp32 (exact loss term) + p_u
//   Inputs scaled by sqrt(30*log2e) so fp8 MFMA emits acc = 30*log2e*cos
//   -> hot epilogue is exp2+add+max, UNSHIFTED domain (max p = e^30, fp32-ok).
//   k_main: R12 epilogue (raw v_exp_f32, SQK fold) with the M-tiling lever:
//     2 M-tiles (32 rows) per wave. R12 post-mortem cycle accounting: 1-M-tile
//     reads 16 B of B per logit -> 102k L1-return cyc/CU = 42.7 us >> 26 us
//     MFMA floor -> the ~60us invariant (R6/R8/R11/R12) is L1-BW, immune to
//     ILP (R12: two chains, zero effect) and epilogue diet (R11). 2-M-tile
//     halves B bytes/logit -> 21 us L1 < 26 us MFMA -> MFMA-bound.
//     Grid stays FULL (256 cgs x 8 rgs), pads computed (zero rows -> p=1,
//     PADC-corrected): R9 (250-grid) and R10 (early return) both broke the
//     blockid%8 XCD mapping -> 91-128 MB cross-XCD misses. R6 proved this
//     exact full-grid 2-M structure clean. launch_bounds(256,5) = ~102-VGPR
//     cap over the ~90-reg footprint (R7 lesson: tight caps spill).
//   k_final: reduce 256 partials/row; S' = S - 2400 - p_u + p_adj;
//     loss = log(S') - 30*tl; acc via max compare; mean.
#define DIM    256
#define BATCH  1024
#define NCLS   100000
#define NCT    256                     // class groups
#define TPG    25                     // 16-class tiles per group
#define NCLS_PAD (NCT * TPG * 16)      // 102400
#define PADC   2400.0f                 // pad classes' exact sum contribution
#define RG     8                       // row groups (128 rows per block)
#define WGTBLK (NCLS_PAD / 16)         // 6400 weight tiles
#define CLIPV  0.9999999f              // 1 - 1e-7 (matches ref fp32 clip)
#define COSM   0.98006657784124163f    // cos(0.2)
#define SINM   0.19866933079506122f    // sin(0.2)
#define K30L2E 43.280851226668903f     // 30 * log2(e)
#define SQK    6.5788184f              // sqrt(30*log2(e)) input pre-scale

typedef __attribute__((ext_vector_type(4))) float floatx4;
typedef __attribute__((ext_vector_type(2))) unsigned long ulong2v;  // 16 B

// ws layout (~28.6 MB)
#define EMBF_OFF 0                                    // 256 KB fp8 emb frags
#define WGTF_OFF (256 * 1024)                         // 26.2 MB fp8 wgt frags
#define TL_OFF   (WGTF_OFF + (size_t)NCLS_PAD * DIM)  // 4 KB adj target cos
#define PU_OFF   (TL_OFF + 4096)                      // 4 KB unadj target p
#define SP_OFF   (PU_OFF + 4096)                      // 256x1024 f32 partials
#define MP_OFF   (SP_OFF + (size_t)NCT * BATCH * 4)   // 256x1024 u32 partials

// ---- k_prep: one launch, three segments ----------------------------------
// Fragment layout: byte (row,k) -> tile(row>>4)*4096 + (s>>1)*1024 + lane*16
// + (s&1)*8 + (k&7), s=k>>5, lane=(row&15)+16*((k>>3)&3).
__global__ __launch_bounds__(256) void k_prep(
        const float* __restrict__ emb, const float* __restrict__ wgt,
        const int* __restrict__ labels,
        unsigned char* __restrict__ emb8f, unsigned char* __restrict__ wgt8f,
        float* __restrict__ TL, float* __restrict__ PU) {
    const int b = blockIdx.x;
    const int tid = threadIdx.x;
    const int w = tid >> 6, l = tid & 63;
    const int sub = w * 4 + (l >> 4);             // row-in-block 0..15
    const int l16 = l & 15;                       // 16 floats per lane

    if (b < 64 + WGTBLK) {                        // --- normalize -> fp8 ---
        const bool isEmb = (b < 64);
        const float* src = isEmb ? emb : wgt;
        unsigned char* dst = isEmb ? emb8f : wgt8f;
        const int nvalid = isEmb ? BATCH : NCLS;
        const int r = (isEmb ? b : b - 64) * 16 + sub;
        const int r16 = r & 15;
        float v[16];
        float ss = 0.f;
        if (r < nvalid) {
            const float* rp = src + (size_t)r * DIM + l16 * 16;
#pragma unroll
            for (int i = 0; i < 4; ++i) {
                float4 a = *(const float4*)(rp + i * 4);
                v[i*4+0]=a.x; v[i*4+1]=a.y; v[i*4+2]=a.z; v[i*4+3]=a.w;
                ss += a.x*a.x + a.y*a.y + a.z*a.z + a.w*a.w;
            }
        } else {
#pragma unroll
            for (int i = 0; i < 16; ++i) v[i] = 0.f;   // pad class -> zeros
        }
#pragma unroll
        for (int k = 1; k < 16; k <<= 1) ss += __shfl_xor(ss, k);
        // scale by SQK so A.B = 30*log2e*cos  (exp2(acc) needs no shift)
        const float sc = SQK / fmaxf(sqrtf(ss), 1e-12f);
        unsigned char* tb = dst + (size_t)(r >> 4) * 4096;
#pragma unroll
        for (int h = 0; h < 2; ++h) {             // two 8-byte k-groups/lane
            const int g = 2 * l16 + h;            // k = 8g..8g+7
            const int s = g >> 2, q = g & 3;
            int p0 = 0, p1 = 0;
            p0 = __builtin_amdgcn_cvt_pk_fp8_f32(v[h*8+0]*sc, v[h*8+1]*sc, p0, false);
            p0 = __builtin_amdgcn_cvt_pk_fp8_f32(v[h*8+2]*sc, v[h*8+3]*sc, p0, true);
            p1 = __builtin_amdgcn_cvt_pk_fp8_f32(v[h*8+4]*sc, v[h*8+5]*sc, p1, false);
            p1 = __builtin_amdgcn_cvt_pk_fp8_f32(v[h*8+6]*sc, v[h*8+7]*sc, p1, true);
            uint2 o; o.x = (unsigned)p0; o.y = (unsigned)p1;
            *(uint2*)(tb + (s >> 1) * 1024 + (r16 + 16 * q) * 16 + (s & 1) * 8) = o;
        }
    } else {                                      // --- target row pass ---
        const int r = (b - 64 - WGTBLK) * 16 + sub;
        const int lbl = labels[r];
        const float* ep = emb + (size_t)r * DIM + l16 * 16;
        const float* wp = wgt + (size_t)lbl * DIM + l16 * 16;
        float de = 0.f, dw = 0.f, dd = 0.f;
#pragma unroll
        for (int i = 0; i < 4; ++i) {
            float4 a = *(const float4*)(ep + i * 4);
            float4 bq = *(const float4*)(wp + i * 4);
            de += a.x*a.x + a.y*a.y + a.z*a.z + a.w*a.w;
            dw += bq.x*bq.x + bq.y*bq.y + bq.z*bq.z + bq.w*bq.w;
            dd += a.x*bq.x + a.y*bq.y + a.z*bq.z + a.w*bq.w;
        }
#pragma unroll
        for (int k = 1; k < 16; k <<= 1) {
            de += __shfl_xor(de, k); dw += __shfl_xor(dw, k); dd += __shfl_xor(dd, k);
        }
        if (l16 == 0) {
            float t = dd / (fmaxf(sqrtf(de), 1e-12f) * fmaxf(sqrtf(dw), 1e-12f));
            t = fminf(fmaxf(t, -CLIPV), CLIPV);
            PU[r] = __builtin_amdgcn_exp2f(t * K30L2E);   // unadjusted p
            TL[r] = t * COSM - sqrtf(fmaxf(1.f - t * t, 0.f)) * SINM;
        }
    }
}

// ---------------- k_main: fused GEMM + register softmax partials ----------
// 2 M-tiles (32 rows) per wave: halves B bytes/logit -> MFMA-bound.
__global__ __launch_bounds__(256, 5) void k_main(
        const unsigned char* __restrict__ wgt8f,
        const unsigned char* __restrict__ emb8f,
        float* __restrict__ SP, unsigned* __restrict__ MP) {
    const int cg = blockIdx.x;            // class group; XCD = blockid % 8
    const int rg = blockIdx.y;            // row group 0..7
    const int tid = threadIdx.x;
    const int w = tid >> 6, l = tid & 63;
    const int r16 = l & 15, q = l >> 4;
    const int rowbase = rg * 128 + w * 32;   // wave's 32 rows (2 M-tiles)

    // A-fragments held in registers the whole kernel (fragment layout)
    long af[2][8];
#pragma unroll
    for (int mt = 0; mt < 2; ++mt) {
        const ulong2v* ap =
            (const ulong2v*)(emb8f + (size_t)((rowbase >> 4) + mt) * 4096) + l;
#pragma unroll
        for (int p = 0; p < 4; ++p) {
            ulong2v v = ap[p * 64];
            af[mt][2*p]   = (long)v.x;
            af[mt][2*p+1] = (long)v.y;
        }
    }

    float sum[2][4] = {{0.f,0.f,0.f,0.f},{0.f,0.f,0.f,0.f}};
    float mx [2][4] = {{0.f,0.f,0.f,0.f},{0.f,0.f,0.f,0.f}};  // max of p

    const ulong2v* bp = (const ulong2v*)(wgt8f + (size_t)(cg * TPG) * 4096) + l;
#pragma unroll 1
    for (int t = 0; t < TPG; ++t, bp += 256) {
        long bf[8];
#pragma unroll
        for (int p = 0; p < 4; ++p) {             // 4 x 1KB coalesced
            ulong2v v = bp[p * 64];
            bf[2*p]   = (long)v.x;
            bf[2*p+1] = (long)v.y;
        }
        floatx4 acc0 = {0.f, 0.f, 0.f, 0.f};
        floatx4 acc1 = {0.f, 0.f, 0.f, 0.f};
#pragma unroll
        for (int s = 0; s < 8; ++s) {             // 2 independent chains
            acc0 = __builtin_amdgcn_mfma_f32_16x16x32_fp8_fp8(af[0][s], bf[s], acc0, 0, 0, 0);
            acc1 = __builtin_amdgcn_mfma_f32_16x16x32_fp8_fp8(af[1][s], bf[s], acc1, 0, 0, 0);
        }
        // acc = 30*log2e*cos (scale folded into fp8); raw v_exp_f32:
        // 3 ops/logit, no clip, no label check.
#pragma unroll
        for (int r = 0; r < 4; ++r) {
            const float p0 = __builtin_amdgcn_exp2f(acc0[r]);
            const float p1 = __builtin_amdgcn_exp2f(acc1[r]);
            sum[0][r] += p0;
            sum[1][r] += p1;
            mx[0][r] = fmaxf(mx[0][r], p0);
            mx[1][r] = fmaxf(mx[1][r], p1);
        }
    }

    // one butterfly per wave (over the 16 class-columns)
#pragma unroll
    for (int k = 1; k < 16; k <<= 1)
#pragma unroll
        for (int mt = 0; mt < 2; ++mt)
#pragma unroll
            for (int r = 0; r < 4; ++r) {
                sum[mt][r] += __shfl_xor(sum[mt][r], k);
                mx[mt][r] = fmaxf(mx[mt][r], __shfl_xor(mx[mt][r], k));
            }
    if (r16 < 4) {
#pragma unroll
        for (int mt = 0; mt < 2; ++mt) {
            float sv = sum[mt][0], mv = mx[mt][0];
            if (r16 == 1) { sv = sum[mt][1]; mv = mx[mt][1]; }
            else if (r16 == 2) { sv = sum[mt][2]; mv = mx[mt][2]; }
            else if (r16 == 3) { sv = sum[mt][3]; mv = mx[mt][3]; }
            const int row = rowbase + mt * 16 + q * 4 + r16;
            SP[cg * BATCH + row] = sv;
            MP[cg * BATCH + row] = __float_as_uint(mv);
        }
    }
}

// ---------------- k_final: reduce partials + loss/acc + mean -------------
__global__ __launch_bounds__(256) void k_final(
        const float* __restrict__ SP, const unsigned* __restrict__ MP,
        const float* __restrict__ TL, const float* __restrict__ PU,
        float* __restrict__ out) {
    __shared__ float    ls[16][16];
    __shared__ unsigned lm[16][16];
    const int tid = threadIdx.x;
    const int r16 = tid & 15;                 // row within block
    const int c   = tid >> 4;                 // partial-chunk lane
    const int row = blockIdx.x * 16 + r16;
    float s = 0.f;
    unsigned m = 0u;
    for (int b = c; b < NCT; b += 16) {       // 16 iters, 64B-coalesced
        s += SP[(size_t)b * BATCH + row];
        const unsigned v = MP[(size_t)b * BATCH + row];
        m = v > m ? v : m;
    }
    ls[c][r16] = s; lm[c][r16] = m;
    __syncthreads();
    float loss = 0.f, corr = 0.f;
    if (tid < 16) {
        float st = 0.f; unsigned mt = 0u;
#pragma unroll
        for (int i = 0; i < 16; ++i) {
            st += ls[i][tid];
            mt = lm[i][tid] > mt ? lm[i][tid] : mt;
        }
        const int r = blockIdx.x * 16 + tid;
        const float tl = TL[r];
        const float padj = __builtin_amdgcn_exp2f(tl * K30L2E);
        // pads contribute exp2(0)=1.0 exactly -> subtract the constant;
        // swap target p: unadjusted -> margin-adjusted
        st = st - PADC - PU[r] + padj;
        loss = logf(st) - 30.f * tl;          // logsumexp - target logit
        corr = (padj >= __uint_as_float(mt)) ? 1.f : 0.f;  // pads (p=1) never win max
    }
#pragma unroll
    for (int k = 1; k < 16; k <<= 1) {        // lanes 16..63 carry zeros
        loss += __shfl_xor(loss, k);
        corr += __shfl_xor(corr, k);
    }
    if (tid == 0) {
        atomicAdd(out + 0, loss * (1.f / 1024.f));
        atomicAdd(out + 1, corr * (1.f / 1024.f));
    }
}

extern "C" void kernel_launch(void* const* d_in, const int* in_sizes, int n_in,
                              void* d_out, int out_size, void* d_ws, size_t ws_size,
                              hipStream_t stream) {
    (void)in_sizes; (void)n_in; (void)out_size; (void)ws_size;
    const float* emb    = (const float*)d_in[0];
    const float* wgt    = (const float*)d_in[1];
    const int*   labels = (const int*)d_in[2];
    char* ws = (char*)d_ws;
    unsigned char* emb8f = (unsigned char*)(ws + EMBF_OFF);
    unsigned char* wgt8f = (unsigned char*)(ws + WGTF_OFF);
    float*    TL = (float*)(ws + TL_OFF);
    float*    PU = (float*)(ws + PU_OFF);
    float*    SP = (float*)(ws + SP_OFF);
    unsigned* MP = (unsigned*)(ws + MP_OFF);

    hipMemsetAsync(d_out, 0, 2 * sizeof(float), stream);  // k_final accumulates
    k_prep<<<64 + WGTBLK + 64, 256, 0, stream>>>(emb, wgt, labels,
                                                 emb8f, wgt8f, TL, PU);
    k_main<<<dim3(NCT, RG), 256, 0, stream>>>(wgt8f, emb8f, SP, MP);
    k_final<<<64, 256, 0, stream>>>(SP, MP, TL, PU, (float*)d_out);
}